// Round 21
// baseline (2116.100 us; speedup 1.0000x reference)
//
#include <hip/hip_runtime.h>
#include <hip/hip_bf16.h>

#define B_ 128
#define T_ 64
#define H_ 256
#define E_ 256
#define L_ 512
#define V_ 30522
#define EOS_ 2
#define BH_ (B_ * H_)
#define NTILE_N 239
#define TILES_PER_XCD (8 * NTILE_N)   // 8 slot-groups x 239 N-tiles

typedef __attribute__((ext_vector_type(8))) short bf16x8;
typedef __attribute__((ext_vector_type(4))) float f32x4;

__device__ __forceinline__ float4 ld4(const float* p) { return *(const float4*)p; }
__device__ __forceinline__ float dot4(float4 a, float4 b) {
  return a.x * b.x + a.y * b.y + a.z * b.z + a.w * b.w;
}
__device__ __forceinline__ float sigf(float x) {
  return __builtin_amdgcn_rcpf(1.f + __expf(-x));
}
__device__ __forceinline__ float tanh_fast(float x) {
  float e = __expf(2.f * x);
  return 1.f - 2.f * __builtin_amdgcn_rcpf(e + 1.f);
}
__device__ __forceinline__ f32x4 mfma16(bf16x8 a, bf16x8 b, f32x4 c) {
  return __builtin_amdgcn_mfma_f32_16x16x32_bf16(a, b, c, 0, 0, 0);
}

// ---------------------------------------------------------------------------
// merged f32 -> bf16 convert for all 6 weight arrays (one launch)
// ---------------------------------------------------------------------------
__global__ __launch_bounds__(256) void conv_all(
    const float* __restrict__ emb, const float* __restrict__ w0i,
    const float* __restrict__ w0h, const float* __restrict__ w1i,
    const float* __restrict__ w1h, const float* __restrict__ wout,
    __hip_bfloat16* __restrict__ dEmb, __hip_bfloat16* __restrict__ dW0i,
    __hip_bfloat16* __restrict__ dW0h, __hip_bfloat16* __restrict__ dW1i,
    __hip_bfloat16* __restrict__ dW1h, __hip_bfloat16* __restrict__ dWout) {
  long i = ((long)blockIdx.x * 256 + threadIdx.x) * 8;
  const float* src; __hip_bfloat16* dst; long off;
  if (i < 7813632L)       { src = emb;  dst = dEmb;  off = i; }
  else if (i < 8075776L)  { src = w0i;  dst = dW0i;  off = i - 7813632L; }
  else if (i < 8337920L)  { src = w0h;  dst = dW0h;  off = i - 8075776L; }
  else if (i < 8600064L)  { src = w1i;  dst = dW1i;  off = i - 8337920L; }
  else if (i < 8862208L)  { src = w1h;  dst = dW1h;  off = i - 8600064L; }
  else if (i < 16675840L) { src = wout; dst = dWout; off = i - 8862208L; }
  else return;
  float4 lo = ld4(src + off), hi = ld4(src + off + 4);
  union { bf16x8 v8; __hip_bfloat16 e[8]; } u;
  u.e[0] = __float2bfloat16(lo.x); u.e[1] = __float2bfloat16(lo.y);
  u.e[2] = __float2bfloat16(lo.z); u.e[3] = __float2bfloat16(lo.w);
  u.e[4] = __float2bfloat16(hi.x); u.e[5] = __float2bfloat16(hi.y);
  u.e[6] = __float2bfloat16(hi.z); u.e[7] = __float2bfloat16(hi.w);
  *(bf16x8*)(dst + off) = u.v8;
}

// zero flags(8192)+tickets(256)+gqx(256)+hsdone_g(16384) = 25088 ints
__global__ __launch_bounds__(256) void reset_cnt(int* __restrict__ c) {
  int i = blockIdx.x * 256 + threadIdx.x;
  if (i < 25088) c[i] = 0;
}

// ---------------------------------------------------------------------------
// init: h_init = z @ W_lat^T + b_lat -> slot 0 of h0 & hs (hi+res)
// ---------------------------------------------------------------------------
__global__ __launch_bounds__(256) void init_kernel(
    const float* __restrict__ z, const float* __restrict__ W_lat,
    const float* __restrict__ b_lat,
    __hip_bfloat16* __restrict__ h0hi, __hip_bfloat16* __restrict__ h0res,
    __hip_bfloat16* __restrict__ hshi, __hip_bfloat16* __restrict__ hsres) {
  int b = blockIdx.x;
  int h = threadIdx.x;
  const float* zr = z + (size_t)b * L_;
  const float* wr = W_lat + (size_t)h * L_;
  float acc = b_lat[h];
  #pragma unroll 4
  for (int l = 0; l < L_; l += 4) acc += dot4(ld4(zr + l), ld4(wr + l));
  __hip_bfloat16 hi = __float2bfloat16(acc);
  __hip_bfloat16 re = __float2bfloat16(acc - __bfloat162float(hi));
  int idx = b * H_ + h;
  h0hi[idx] = hi; h0res[idx] = re;
  hshi[idx] = hi; hsres[idx] = re;
}

// ---------------------------------------------------------------------------
// FUSED persistent kernel, SAME-XCD producer->consumer (R18-R20 structure).
// R21 changes (both target IC/L2 contention that stretches the recurrence):
//  1. Ticket remap for B-tile L2 reuse: tau -> (pair = tau>>1, s = tau&1),
//     sg = 2*(pair/239)+s, nt = pair%239. Consecutive tickets process the
//     SAME nt (same WoutB tile) for two slot-groups -> the second block's
//     B reads hit L2. Halves B re-fetch from IC (was ~260MB of FETCH).
//  2. Nontemporal full-line output stores: the coalesced 512B runs stream
//     past L2 (7/9 lines per run are full; edge partials a wash vs RFO).
//     Frees L2/IC for B-tiles and the recurrence's flag round-trips.
// Sync transport FROZEN (atomicAdd both sides; R10/R14 alternatives failed).
// ---------------------------------------------------------------------------
__global__ __launch_bounds__(256, 3) void fused(
    const int* __restrict__ targ, const __hip_bfloat16* __restrict__ embB,
    const __hip_bfloat16* __restrict__ Wih0B, const __hip_bfloat16* __restrict__ Whh0B,
    const float* __restrict__ b_ih0, const float* __restrict__ b_hh0,
    const __hip_bfloat16* __restrict__ Wih1B, const __hip_bfloat16* __restrict__ Whh1B,
    const float* __restrict__ b_ih1, const float* __restrict__ b_hh1,
    __hip_bfloat16* __restrict__ h0hi, __hip_bfloat16* __restrict__ h0res,
    __hip_bfloat16* __restrict__ hshi, __hip_bfloat16* __restrict__ hsres,
    const __hip_bfloat16* __restrict__ Wb, const float* __restrict__ bout,
    float* __restrict__ out,
    int* __restrict__ flags, int* __restrict__ tickets,
    int* __restrict__ gqx, int* __restrict__ hsdone_g) {
  __shared__ int role_sh, gang_sh, tile_sh;
  __shared__ char smem[32768];

  const int tid = threadIdx.x;
  if (tid == 0) {
    unsigned xcd;
    asm volatile("s_getreg_b32 %0, hwreg(HW_REG_XCC_ID)" : "=s"(xcd));
    xcd &= 7u;
    role_sh = __hip_atomic_fetch_add(tickets + xcd * 32, 1, __ATOMIC_RELAXED,
                                     __HIP_MEMORY_SCOPE_AGENT);
    gang_sh = (int)xcd;
  }
  __syncthreads();
  const int role = role_sh;
  const int gang = gang_sh;
  const int lane = tid & 63;

  if (role < 32) {
    // ================= LSTM worker (R13-exact math, priority-boosted) ======
    __builtin_amdgcn_s_setprio(1);
    const bool isL0 = role < 16;
    const int chunk = role & 15;
    int* flag0 = flags + gang * 1024;
    int* flag1 = flag0 + 512;

    const int wave = tid >> 6;
    const int arow = lane & 15;
    const int klo = lane >> 4;
    const int hcol = chunk * 16 + arow;
    const int brow0 = gang * 16;
    const int myrow = brow0 + arow;

    const __hip_bfloat16* W1 = isL0 ? Wih0B : Wih1B;
    const __hip_bfloat16* W2 = isL0 ? Whh0B : Whh1B;
    bf16x8 bw1[8], bw2[8];
    {
      const size_t wrow = (size_t)(wave * 256 + hcol) * 256;
      #pragma unroll
      for (int ks = 0; ks < 8; ++ks) {
        bw1[ks] = *(const bf16x8*)(W1 + wrow + ks * 32 + klo * 8);
        bw2[ks] = *(const bf16x8*)(W2 + wrow + ks * 32 + klo * 8);
      }
    }

    const int erow = tid >> 4;
    const int ecol = tid & 15;
    const float* bi = isL0 ? b_ih0 : b_ih1;
    const float* bh = isL0 ? b_hh0 : b_hh1;
    const int ehcol = chunk * 16 + ecol;
    const float bias_i = bi[ehcol] + bh[ehcol];
    const float bias_f = bi[256 + ehcol] + bh[256 + ehcol];
    const float bias_g = bi[512 + ehcol] + bh[512 + ehcol];
    const float bias_o = bi[768 + ehcol] + bh[768 + ehcol];
    float c_state = 0.f;

    typedef float GL[16][17];
    GL* glds = (GL*)smem;

    for (int t = 0; t < T_; ++t) {
      {
        const int need0 = isL0 ? t : t + 1;
        const int need1 = isL0 ? 0 : t;
        if (tid < 64) {
          int* p = nullptr; int need = 0;
          if (lane < 16) { p = flag0 + lane * 32; need = need0; }
          else if (lane < 32) { p = flag1 + (lane - 16) * 32; need = need1; }
          int it = 0;
          for (;;) {
            bool ok = true;
            if (p && need > 0) ok = (atomicAdd(p, 0) >= need);
            if (__all(ok)) break;
            if (++it >= (1 << 15)) break;   // loud failure, not a hang
            __builtin_amdgcn_s_sleep(1);
          }
        }
        __syncthreads();
      }

      f32x4 acc0 = (f32x4){0.f, 0.f, 0.f, 0.f};
      f32x4 acc1 = (f32x4){0.f, 0.f, 0.f, 0.f};
      if (isL0) {
        int tok = (t == 0) ? EOS_ : targ[myrow * T_ + t - 1];
        const __hip_bfloat16* xp = embB + (size_t)tok * E_;
        const __hip_bfloat16* hhp = h0hi + (size_t)t * BH_ + myrow * H_;
        const __hip_bfloat16* hrp = h0res + (size_t)t * BH_ + myrow * H_;
        #pragma unroll
        for (int ks = 0; ks < 8; ++ks) {
          const int ko = ks * 32 + klo * 8;
          bf16x8 ax = *(const bf16x8*)(xp + ko);
          bf16x8 ahh = *(const bf16x8*)(hhp + ko);
          bf16x8 ahr = *(const bf16x8*)(hrp + ko);
          if (ks & 1) {
            acc1 = mfma16(ax, bw1[ks], acc1);
            acc1 = mfma16(ahh, bw2[ks], acc1);
            acc1 = mfma16(ahr, bw2[ks], acc1);
          } else {
            acc0 = mfma16(ax, bw1[ks], acc0);
            acc0 = mfma16(ahh, bw2[ks], acc0);
            acc0 = mfma16(ahr, bw2[ks], acc0);
          }
        }
      } else {
        const __hip_bfloat16* xhp = h0hi + (size_t)(t + 1) * BH_ + myrow * H_;
        const __hip_bfloat16* xrp = h0res + (size_t)(t + 1) * BH_ + myrow * H_;
        const __hip_bfloat16* hhp = hshi + (size_t)t * BH_ + myrow * H_;
        const __hip_bfloat16* hrp = hsres + (size_t)t * BH_ + myrow * H_;
        #pragma unroll
        for (int ks = 0; ks < 8; ++ks) {
          const int ko = ks * 32 + klo * 8;
          bf16x8 axh = *(const bf16x8*)(xhp + ko);
          bf16x8 axr = *(const bf16x8*)(xrp + ko);
          bf16x8 ahh = *(const bf16x8*)(hhp + ko);
          bf16x8 ahr = *(const bf16x8*)(hrp + ko);
          if (ks & 1) {
            acc1 = mfma16(axh, bw1[ks], acc1);
            acc1 = mfma16(axr, bw1[ks], acc1);
            acc1 = mfma16(ahh, bw2[ks], acc1);
            acc1 = mfma16(ahr, bw2[ks], acc1);
          } else {
            acc0 = mfma16(axh, bw1[ks], acc0);
            acc0 = mfma16(axr, bw1[ks], acc0);
            acc0 = mfma16(ahh, bw2[ks], acc0);
            acc0 = mfma16(ahr, bw2[ks], acc0);
          }
        }
      }
      #pragma unroll
      for (int r = 0; r < 4; ++r)
        glds[tid >> 6][klo * 4 + r][arow] = acc0[r] + acc1[r];
      __syncthreads();

      {
        float gi = glds[0][erow][ecol] + bias_i;
        float gf = glds[1][erow][ecol] + bias_f;
        float gg = glds[2][erow][ecol] + bias_g;
        float go = glds[3][erow][ecol] + bias_o;
        float iv = sigf(gi), fv = sigf(gf), gv = tanh_fast(gg), ov = sigf(go);
        c_state = fv * c_state + iv * gv;
        float h = ov * tanh_fast(c_state);
        __hip_bfloat16 hi = __float2bfloat16(h);
        __hip_bfloat16 re = __float2bfloat16(h - __bfloat162float(hi));
        size_t off = (size_t)(t + 1) * BH_ + (size_t)(brow0 + erow) * H_ + ehcol;
        (isL0 ? h0hi : hshi)[off] = hi;
        (isL0 ? h0res : hsres)[off] = re;
      }

      __syncthreads();   // vmcnt drain: stores are in this XCD's L2
      if (tid == 0) {
        atomicAdd((isL0 ? flag0 : flag1) + chunk * 32, 1);
        if (!isL0) atomicAdd(hsdone_g + (gang * 64 + t) * 32, 1);
      }
    }
    __builtin_amdgcn_s_setprio(0);
    // fall through: finished lstm workers join this XCD's gemm pool
  }

  // ================= GEMM worker (same-XCD tiles only) =================
  __hip_bfloat16* ldsA = (__hip_bfloat16*)smem;            // [2][4096]
  __hip_bfloat16* ldsB = (__hip_bfloat16*)(smem + 16384);  // [2][4096]
  const int wave = tid >> 6;
  const int wr = wave >> 1, wc = wave & 1;
  const int row_in = lane & 15;
  const int kgrp = lane >> 4;

  for (;;) {
    if (tid == 0) tile_sh = atomicAdd(gqx + gang * 32, 1);
    __syncthreads();
    const int tau = tile_sh;
    if (tau >= TILES_PER_XCD) return;
    // B-reuse pairing: consecutive tickets share nt (same B tile), two sgs
    const int pairIdx = tau >> 1;
    const int s = tau & 1;
    const int sgp = pairIdx / NTILE_N;
    const int nt = pairIdx - sgp * NTILE_N;
    const int sg = sgp * 2 + s;            // slot group: t = sg*8 .. sg*8+7
    const int n0 = nt * 128;
    const int t0 = sg * 8;

    // wait: last slot of the group done (monotone completion subsumes rest)
    if (tid == 0) {
      int* p = hsdone_g + (gang * 64 + t0 + 7) * 32;
      int it = 0;
      while (atomicAdd(p, 0) < 16 && it < (1 << 15)) {
        __builtin_amdgcn_s_sleep(32);
        ++it;
      }
    }
    __syncthreads();

    // A row r (0..127): t = t0 + (r>>4), b = gang*16 + (r&15)
    auto stage = [&](int kb, int buf) {
      #pragma unroll
      for (int p = 0; p < 2; ++p) {
        int slot = p * 256 + wave * 64 + lane;
        int row = slot >> 2;
        int kd = ((slot & 3) + (row >> 1)) & 3;   // swizzled source granule
        const __hip_bfloat16* srcA =
            hshi + (size_t)(t0 + (row >> 4) + 1) * BH_ +
            (size_t)(gang * 16 + (row & 15)) * H_ + kb * 32 + kd * 8;
        int rn = n0 + row; if (rn >= V_) rn = V_ - 1;
        const __hip_bfloat16* srcB = Wb + (size_t)rn * H_ + kb * 32 + kd * 8;
        __hip_bfloat16* dstA = ldsA + buf * 4096 + (p * 2048 + wave * 512);
        __hip_bfloat16* dstB = ldsB + buf * 4096 + (p * 2048 + wave * 512);
        __builtin_amdgcn_global_load_lds(
            (const __attribute__((address_space(1))) unsigned int*)srcA,
            (__attribute__((address_space(3))) unsigned int*)dstA, 16, 0, 0);
        __builtin_amdgcn_global_load_lds(
            (const __attribute__((address_space(1))) unsigned int*)srcB,
            (__attribute__((address_space(3))) unsigned int*)dstB, 16, 0, 0);
      }
    };

    f32x4 acc[4][4];
    #pragma unroll
    for (int i = 0; i < 4; ++i)
      #pragma unroll
      for (int j = 0; j < 4; ++j) acc[i][j] = (f32x4){0.f, 0.f, 0.f, 0.f};

    stage(0, 0);
    __syncthreads();

    int buf = 0;
    for (int kb = 0; kb < 8; ++kb) {
      if (kb < 7) stage(kb + 1, buf ^ 1);
      bf16x8 a[4], b[4];
      #pragma unroll
      for (int mi = 0; mi < 4; ++mi) {
        int row = wr * 64 + mi * 16 + row_in;
        int g = (kgrp - (row >> 1)) & 3;
        a[mi] = *(const bf16x8*)(ldsA + buf * 4096 + row * 32 + g * 8);
      }
      #pragma unroll
      for (int ni = 0; ni < 4; ++ni) {
        int row = wc * 64 + ni * 16 + row_in;
        int g = (kgrp - (row >> 1)) & 3;
        b[ni] = *(const bf16x8*)(ldsB + buf * 4096 + row * 32 + g * 8);
      }
      #pragma unroll
      for (int mi = 0; mi < 4; ++mi)
        #pragma unroll
        for (int ni = 0; ni < 4; ++ni)
          acc[mi][ni] = mfma16(a[mi], b[ni], acc[mi][ni]);
      __syncthreads();
      buf ^= 1;
    }

    // ---- coalesced epilogue: 4 slabs of 32 rows through LDS, NT stores ----
    float biasv[4];
    #pragma unroll
    for (int ni = 0; ni < 4; ++ni) {
      int v = n0 + wc * 64 + ni * 16 + row_in;
      biasv[ni] = (v < V_) ? bout[v] : 0.f;
    }
    float* ldsf = (float*)smem;   // [32][134] f32 = 17152B, reuses ldsA/B
    #pragma unroll
    for (int s4 = 0; s4 < 4; ++s4) {
      if (wr == (s4 >> 1)) {
        #pragma unroll
        for (int mloc = 0; mloc < 2; ++mloc) {
          const int mi = (s4 & 1) * 2 + mloc;
          #pragma unroll
          for (int ni = 0; ni < 4; ++ni)
            #pragma unroll
            for (int r = 0; r < 4; ++r)
              ldsf[(mloc * 16 + kgrp * 4 + r) * 134 + wc * 64 + ni * 16 + row_in]
                  = acc[mi][ni][r] + biasv[ni];
        }
      }
      __syncthreads();
      {
        const int row_l = tid >> 3;     // 0..31
        const int cg = tid & 7;         // 16-col group
        const int m = s4 * 32 + row_l;
        const int tt = t0 + (m >> 4);
        const int bb_ = gang * 16 + (m & 15);
        float* orow = out + ((size_t)bb_ * T_ + tt) * V_;
        const int v0 = n0 + cg * 16;
        const float* src = ldsf + row_l * 134 + cg * 16;
        if (v0 + 15 < V_) {
          #pragma unroll
          for (int k = 0; k < 8; ++k) {
            float2 val = *(const float2*)(src + k * 2);
            __builtin_nontemporal_store(*(const double*)&val,
                                        (double*)(orow + v0 + k * 2));
          }
        } else {
          for (int e = 0; e < 16 && v0 + e < V_; ++e)
            orow[v0 + e] = src[e];
        }
      }
      __syncthreads();
    }
  }
}

// ---------------------------------------------------------------------------
extern "C" void kernel_launch(void* const* d_in, const int* in_sizes, int n_in,
                              void* d_out, int out_size, void* d_ws, size_t ws_size,
                              hipStream_t stream) {
  const float* z     = (const float*)d_in[0];
  const int*   targ  = (const int*)d_in[1];
  const float* emb   = (const float*)d_in[2];
  const float* W_ih0 = (const float*)d_in[3];
  const float* W_hh0 = (const float*)d_in[4];
  const float* b_ih0 = (const float*)d_in[5];
  const float* b_hh0 = (const float*)d_in[6];
  const float* W_ih1 = (const float*)d_in[7];
  const float* W_hh1 = (const float*)d_in[8];
  const float* b_ih1 = (const float*)d_in[9];
  const float* b_hh1 = (const float*)d_in[10];
  const float* W_out = (const float*)d_in[11];
  const float* b_out = (const float*)d_in[12];
  const float* W_lat = (const float*)d_in[13];
  const float* b_lat = (const float*)d_in[14];
  float* out = (float*)d_out;

  char* ws = (char*)d_ws;
  __hip_bfloat16* h0hi  = (__hip_bfloat16*)(ws);              // 4,259,840
  __hip_bfloat16* h0res = (__hip_bfloat16*)(ws + 4259840);
  __hip_bfloat16* hshi  = (__hip_bfloat16*)(ws + 8519680);
  __hip_bfloat16* hsres = (__hip_bfloat16*)(ws + 12779520);
  __hip_bfloat16* embB  = (__hip_bfloat16*)(ws + 17039360);   // 15,627,264
  __hip_bfloat16* Wih0B = (__hip_bfloat16*)(ws + 32666624);   // 524,288
  __hip_bfloat16* Whh0B = (__hip_bfloat16*)(ws + 33190912);
  __hip_bfloat16* Wih1B = (__hip_bfloat16*)(ws + 33715200);
  __hip_bfloat16* Whh1B = (__hip_bfloat16*)(ws + 34239488);
  __hip_bfloat16* WoutB = (__hip_bfloat16*)(ws + 34763776);   // 15,627,264
  int* flags    = (int*)(ws + 50391040);                      // 8192 ints
  int* tickets  = flags + 8192;                               // 256 ints
  int* gqx      = flags + 8448;                               // 256 ints
  int* hsdone_g = flags + 8704;                               // 16384 ints

  reset_cnt<<<98, 256, 0, stream>>>(flags);
  conv_all<<<8144, 256, 0, stream>>>(emb, W_ih0, W_hh0, W_ih1, W_hh1, W_out,
                                     embB, Wih0B, Whh0B, Wih1B, Whh1B, WoutB);
  init_kernel<<<128, 256, 0, stream>>>(z, W_lat, b_lat, h0hi, h0res, hshi, hsres);

  fused<<<768, 256, 0, stream>>>(
      targ, embB,
      Wih0B, Whh0B, b_ih0, b_hh0,
      Wih1B, Whh1B, b_ih1, b_hh1,
      h0hi, h0res, hshi, hsres,
      WoutB, b_out, out,
      flags, tickets, gqx, hsdone_g);
}

// Round 22
// 917.747 us; speedup vs baseline: 2.3058x; 2.3058x over previous
//
#include <hip/hip_runtime.h>
#include <hip/hip_bf16.h>

#define B_ 128
#define T_ 64
#define H_ 256
#define E_ 256
#define L_ 512
#define V_ 30522
#define EOS_ 2
#define BH_ (B_ * H_)
#define NTILE_N 239
#define TILES_PER_XCD (8 * NTILE_N)   // 8 slot-groups x 239 N-tiles

typedef __attribute__((ext_vector_type(8))) short bf16x8;
typedef __attribute__((ext_vector_type(4))) float f32x4;

__device__ __forceinline__ float4 ld4(const float* p) { return *(const float4*)p; }
__device__ __forceinline__ float dot4(float4 a, float4 b) {
  return a.x * b.x + a.y * b.y + a.z * b.z + a.w * b.w;
}
__device__ __forceinline__ float sigf(float x) {
  return __builtin_amdgcn_rcpf(1.f + __expf(-x));
}
__device__ __forceinline__ float tanh_fast(float x) {
  float e = __expf(2.f * x);
  return 1.f - 2.f * __builtin_amdgcn_rcpf(e + 1.f);
}
__device__ __forceinline__ f32x4 mfma16(bf16x8 a, bf16x8 b, f32x4 c) {
  return __builtin_amdgcn_mfma_f32_16x16x32_bf16(a, b, c, 0, 0, 0);
}

// ---------------------------------------------------------------------------
// merged f32 -> bf16 convert for all 6 weight arrays (one launch)
// ---------------------------------------------------------------------------
__global__ __launch_bounds__(256) void conv_all(
    const float* __restrict__ emb, const float* __restrict__ w0i,
    const float* __restrict__ w0h, const float* __restrict__ w1i,
    const float* __restrict__ w1h, const float* __restrict__ wout,
    __hip_bfloat16* __restrict__ dEmb, __hip_bfloat16* __restrict__ dW0i,
    __hip_bfloat16* __restrict__ dW0h, __hip_bfloat16* __restrict__ dW1i,
    __hip_bfloat16* __restrict__ dW1h, __hip_bfloat16* __restrict__ dWout) {
  long i = ((long)blockIdx.x * 256 + threadIdx.x) * 8;
  const float* src; __hip_bfloat16* dst; long off;
  if (i < 7813632L)       { src = emb;  dst = dEmb;  off = i; }
  else if (i < 8075776L)  { src = w0i;  dst = dW0i;  off = i - 7813632L; }
  else if (i < 8337920L)  { src = w0h;  dst = dW0h;  off = i - 8075776L; }
  else if (i < 8600064L)  { src = w1i;  dst = dW1i;  off = i - 8337920L; }
  else if (i < 8862208L)  { src = w1h;  dst = dW1h;  off = i - 8600064L; }
  else if (i < 16675840L) { src = wout; dst = dWout; off = i - 8862208L; }
  else return;
  float4 lo = ld4(src + off), hi = ld4(src + off + 4);
  union { bf16x8 v8; __hip_bfloat16 e[8]; } u;
  u.e[0] = __float2bfloat16(lo.x); u.e[1] = __float2bfloat16(lo.y);
  u.e[2] = __float2bfloat16(lo.z); u.e[3] = __float2bfloat16(lo.w);
  u.e[4] = __float2bfloat16(hi.x); u.e[5] = __float2bfloat16(hi.y);
  u.e[6] = __float2bfloat16(hi.z); u.e[7] = __float2bfloat16(hi.w);
  *(bf16x8*)(dst + off) = u.v8;
}

// zero flags(8192)+tickets(256)+gqx(256)+hsdone_g(16384) = 25088 ints
__global__ __launch_bounds__(256) void reset_cnt(int* __restrict__ c) {
  int i = blockIdx.x * 256 + threadIdx.x;
  if (i < 25088) c[i] = 0;
}

// ---------------------------------------------------------------------------
// init: h_init = z @ W_lat^T + b_lat -> slot 0 of h0 & hs (hi+res)
// ---------------------------------------------------------------------------
__global__ __launch_bounds__(256) void init_kernel(
    const float* __restrict__ z, const float* __restrict__ W_lat,
    const float* __restrict__ b_lat,
    __hip_bfloat16* __restrict__ h0hi, __hip_bfloat16* __restrict__ h0res,
    __hip_bfloat16* __restrict__ hshi, __hip_bfloat16* __restrict__ hsres) {
  int b = blockIdx.x;
  int h = threadIdx.x;
  const float* zr = z + (size_t)b * L_;
  const float* wr = W_lat + (size_t)h * L_;
  float acc = b_lat[h];
  #pragma unroll 4
  for (int l = 0; l < L_; l += 4) acc += dot4(ld4(zr + l), ld4(wr + l));
  __hip_bfloat16 hi = __float2bfloat16(acc);
  __hip_bfloat16 re = __float2bfloat16(acc - __bfloat162float(hi));
  int idx = b * H_ + h;
  h0hi[idx] = hi; h0res[idx] = re;
  hshi[idx] = hi; hsres[idx] = re;
}

// ---------------------------------------------------------------------------
// FUSED persistent kernel, SAME-XCD producer->consumer (R18-R20 structure).
// R22 = R20 epilogue (plain float2 stores -- NT stores amplified writes 3x
// in R21 and are BANNED at any granularity) + R21's B-tile pairing remap
// (proven: FETCH 520 -> 304MB). Sync transport FROZEN.
// ---------------------------------------------------------------------------
__global__ __launch_bounds__(256, 3) void fused(
    const int* __restrict__ targ, const __hip_bfloat16* __restrict__ embB,
    const __hip_bfloat16* __restrict__ Wih0B, const __hip_bfloat16* __restrict__ Whh0B,
    const float* __restrict__ b_ih0, const float* __restrict__ b_hh0,
    const __hip_bfloat16* __restrict__ Wih1B, const __hip_bfloat16* __restrict__ Whh1B,
    const float* __restrict__ b_ih1, const float* __restrict__ b_hh1,
    __hip_bfloat16* __restrict__ h0hi, __hip_bfloat16* __restrict__ h0res,
    __hip_bfloat16* __restrict__ hshi, __hip_bfloat16* __restrict__ hsres,
    const __hip_bfloat16* __restrict__ Wb, const float* __restrict__ bout,
    float* __restrict__ out,
    int* __restrict__ flags, int* __restrict__ tickets,
    int* __restrict__ gqx, int* __restrict__ hsdone_g) {
  __shared__ int role_sh, gang_sh, tile_sh;
  __shared__ char smem[32768];

  const int tid = threadIdx.x;
  if (tid == 0) {
    unsigned xcd;
    asm volatile("s_getreg_b32 %0, hwreg(HW_REG_XCC_ID)" : "=s"(xcd));
    xcd &= 7u;
    role_sh = __hip_atomic_fetch_add(tickets + xcd * 32, 1, __ATOMIC_RELAXED,
                                     __HIP_MEMORY_SCOPE_AGENT);
    gang_sh = (int)xcd;
  }
  __syncthreads();
  const int role = role_sh;
  const int gang = gang_sh;
  const int lane = tid & 63;

  if (role < 32) {
    // ================= LSTM worker (R13-exact math, priority-boosted) ======
    __builtin_amdgcn_s_setprio(1);
    const bool isL0 = role < 16;
    const int chunk = role & 15;
    int* flag0 = flags + gang * 1024;
    int* flag1 = flag0 + 512;

    const int wave = tid >> 6;
    const int arow = lane & 15;
    const int klo = lane >> 4;
    const int hcol = chunk * 16 + arow;
    const int brow0 = gang * 16;
    const int myrow = brow0 + arow;

    const __hip_bfloat16* W1 = isL0 ? Wih0B : Wih1B;
    const __hip_bfloat16* W2 = isL0 ? Whh0B : Whh1B;
    bf16x8 bw1[8], bw2[8];
    {
      const size_t wrow = (size_t)(wave * 256 + hcol) * 256;
      #pragma unroll
      for (int ks = 0; ks < 8; ++ks) {
        bw1[ks] = *(const bf16x8*)(W1 + wrow + ks * 32 + klo * 8);
        bw2[ks] = *(const bf16x8*)(W2 + wrow + ks * 32 + klo * 8);
      }
    }

    const int erow = tid >> 4;
    const int ecol = tid & 15;
    const float* bi = isL0 ? b_ih0 : b_ih1;
    const float* bh = isL0 ? b_hh0 : b_hh1;
    const int ehcol = chunk * 16 + ecol;
    const float bias_i = bi[ehcol] + bh[ehcol];
    const float bias_f = bi[256 + ehcol] + bh[256 + ehcol];
    const float bias_g = bi[512 + ehcol] + bh[512 + ehcol];
    const float bias_o = bi[768 + ehcol] + bh[768 + ehcol];
    float c_state = 0.f;

    typedef float GL[16][17];
    GL* glds = (GL*)smem;

    for (int t = 0; t < T_; ++t) {
      {
        const int need0 = isL0 ? t : t + 1;
        const int need1 = isL0 ? 0 : t;
        if (tid < 64) {
          int* p = nullptr; int need = 0;
          if (lane < 16) { p = flag0 + lane * 32; need = need0; }
          else if (lane < 32) { p = flag1 + (lane - 16) * 32; need = need1; }
          int it = 0;
          for (;;) {
            bool ok = true;
            if (p && need > 0) ok = (atomicAdd(p, 0) >= need);
            if (__all(ok)) break;
            if (++it >= (1 << 15)) break;   // loud failure, not a hang
            __builtin_amdgcn_s_sleep(1);
          }
        }
        __syncthreads();
      }

      f32x4 acc0 = (f32x4){0.f, 0.f, 0.f, 0.f};
      f32x4 acc1 = (f32x4){0.f, 0.f, 0.f, 0.f};
      if (isL0) {
        int tok = (t == 0) ? EOS_ : targ[myrow * T_ + t - 1];
        const __hip_bfloat16* xp = embB + (size_t)tok * E_;
        const __hip_bfloat16* hhp = h0hi + (size_t)t * BH_ + myrow * H_;
        const __hip_bfloat16* hrp = h0res + (size_t)t * BH_ + myrow * H_;
        #pragma unroll
        for (int ks = 0; ks < 8; ++ks) {
          const int ko = ks * 32 + klo * 8;
          bf16x8 ax = *(const bf16x8*)(xp + ko);
          bf16x8 ahh = *(const bf16x8*)(hhp + ko);
          bf16x8 ahr = *(const bf16x8*)(hrp + ko);
          if (ks & 1) {
            acc1 = mfma16(ax, bw1[ks], acc1);
            acc1 = mfma16(ahh, bw2[ks], acc1);
            acc1 = mfma16(ahr, bw2[ks], acc1);
          } else {
            acc0 = mfma16(ax, bw1[ks], acc0);
            acc0 = mfma16(ahh, bw2[ks], acc0);
            acc0 = mfma16(ahr, bw2[ks], acc0);
          }
        }
      } else {
        const __hip_bfloat16* xhp = h0hi + (size_t)(t + 1) * BH_ + myrow * H_;
        const __hip_bfloat16* xrp = h0res + (size_t)(t + 1) * BH_ + myrow * H_;
        const __hip_bfloat16* hhp = hshi + (size_t)t * BH_ + myrow * H_;
        const __hip_bfloat16* hrp = hsres + (size_t)t * BH_ + myrow * H_;
        #pragma unroll
        for (int ks = 0; ks < 8; ++ks) {
          const int ko = ks * 32 + klo * 8;
          bf16x8 axh = *(const bf16x8*)(xhp + ko);
          bf16x8 axr = *(const bf16x8*)(xrp + ko);
          bf16x8 ahh = *(const bf16x8*)(hhp + ko);
          bf16x8 ahr = *(const bf16x8*)(hrp + ko);
          if (ks & 1) {
            acc1 = mfma16(axh, bw1[ks], acc1);
            acc1 = mfma16(axr, bw1[ks], acc1);
            acc1 = mfma16(ahh, bw2[ks], acc1);
            acc1 = mfma16(ahr, bw2[ks], acc1);
          } else {
            acc0 = mfma16(axh, bw1[ks], acc0);
            acc0 = mfma16(axr, bw1[ks], acc0);
            acc0 = mfma16(ahh, bw2[ks], acc0);
            acc0 = mfma16(ahr, bw2[ks], acc0);
          }
        }
      }
      #pragma unroll
      for (int r = 0; r < 4; ++r)
        glds[tid >> 6][klo * 4 + r][arow] = acc0[r] + acc1[r];
      __syncthreads();

      {
        float gi = glds[0][erow][ecol] + bias_i;
        float gf = glds[1][erow][ecol] + bias_f;
        float gg = glds[2][erow][ecol] + bias_g;
        float go = glds[3][erow][ecol] + bias_o;
        float iv = sigf(gi), fv = sigf(gf), gv = tanh_fast(gg), ov = sigf(go);
        c_state = fv * c_state + iv * gv;
        float h = ov * tanh_fast(c_state);
        __hip_bfloat16 hi = __float2bfloat16(h);
        __hip_bfloat16 re = __float2bfloat16(h - __bfloat162float(hi));
        size_t off = (size_t)(t + 1) * BH_ + (size_t)(brow0 + erow) * H_ + ehcol;
        (isL0 ? h0hi : hshi)[off] = hi;
        (isL0 ? h0res : hsres)[off] = re;
      }

      __syncthreads();   // vmcnt drain: stores are in this XCD's L2
      if (tid == 0) {
        atomicAdd((isL0 ? flag0 : flag1) + chunk * 32, 1);
        if (!isL0) atomicAdd(hsdone_g + (gang * 64 + t) * 32, 1);
      }
    }
    __builtin_amdgcn_s_setprio(0);
    // fall through: finished lstm workers join this XCD's gemm pool
  }

  // ================= GEMM worker (same-XCD tiles only) =================
  __hip_bfloat16* ldsA = (__hip_bfloat16*)smem;            // [2][4096]
  __hip_bfloat16* ldsB = (__hip_bfloat16*)(smem + 16384);  // [2][4096]
  const int wave = tid >> 6;
  const int wr = wave >> 1, wc = wave & 1;
  const int row_in = lane & 15;
  const int kgrp = lane >> 4;

  for (;;) {
    if (tid == 0) tile_sh = atomicAdd(gqx + gang * 32, 1);
    __syncthreads();
    const int tau = tile_sh;
    if (tau >= TILES_PER_XCD) return;
    // B-reuse pairing: consecutive tickets share nt (same B tile), two sgs
    const int pairIdx = tau >> 1;
    const int s = tau & 1;
    const int sgp = pairIdx / NTILE_N;
    const int nt = pairIdx - sgp * NTILE_N;
    const int sg = sgp * 2 + s;            // slot group: t = sg*8 .. sg*8+7
    const int n0 = nt * 128;
    const int t0 = sg * 8;

    // wait: last slot of the group done (monotone completion subsumes rest)
    if (tid == 0) {
      int* p = hsdone_g + (gang * 64 + t0 + 7) * 32;
      int it = 0;
      while (atomicAdd(p, 0) < 16 && it < (1 << 15)) {
        __builtin_amdgcn_s_sleep(32);
        ++it;
      }
    }
    __syncthreads();

    // A row r (0..127): t = t0 + (r>>4), b = gang*16 + (r&15)
    auto stage = [&](int kb, int buf) {
      #pragma unroll
      for (int p = 0; p < 2; ++p) {
        int slot = p * 256 + wave * 64 + lane;
        int row = slot >> 2;
        int kd = ((slot & 3) + (row >> 1)) & 3;   // swizzled source granule
        const __hip_bfloat16* srcA =
            hshi + (size_t)(t0 + (row >> 4) + 1) * BH_ +
            (size_t)(gang * 16 + (row & 15)) * H_ + kb * 32 + kd * 8;
        int rn = n0 + row; if (rn >= V_) rn = V_ - 1;
        const __hip_bfloat16* srcB = Wb + (size_t)rn * H_ + kb * 32 + kd * 8;
        __hip_bfloat16* dstA = ldsA + buf * 4096 + (p * 2048 + wave * 512);
        __hip_bfloat16* dstB = ldsB + buf * 4096 + (p * 2048 + wave * 512);
        __builtin_amdgcn_global_load_lds(
            (const __attribute__((address_space(1))) unsigned int*)srcA,
            (__attribute__((address_space(3))) unsigned int*)dstA, 16, 0, 0);
        __builtin_amdgcn_global_load_lds(
            (const __attribute__((address_space(1))) unsigned int*)srcB,
            (__attribute__((address_space(3))) unsigned int*)dstB, 16, 0, 0);
      }
    };

    f32x4 acc[4][4];
    #pragma unroll
    for (int i = 0; i < 4; ++i)
      #pragma unroll
      for (int j = 0; j < 4; ++j) acc[i][j] = (f32x4){0.f, 0.f, 0.f, 0.f};

    stage(0, 0);
    __syncthreads();

    int buf = 0;
    for (int kb = 0; kb < 8; ++kb) {
      if (kb < 7) stage(kb + 1, buf ^ 1);
      bf16x8 a[4], b[4];
      #pragma unroll
      for (int mi = 0; mi < 4; ++mi) {
        int row = wr * 64 + mi * 16 + row_in;
        int g = (kgrp - (row >> 1)) & 3;
        a[mi] = *(const bf16x8*)(ldsA + buf * 4096 + row * 32 + g * 8);
      }
      #pragma unroll
      for (int ni = 0; ni < 4; ++ni) {
        int row = wc * 64 + ni * 16 + row_in;
        int g = (kgrp - (row >> 1)) & 3;
        b[ni] = *(const bf16x8*)(ldsB + buf * 4096 + row * 32 + g * 8);
      }
      #pragma unroll
      for (int mi = 0; mi < 4; ++mi)
        #pragma unroll
        for (int ni = 0; ni < 4; ++ni)
          acc[mi][ni] = mfma16(a[mi], b[ni], acc[mi][ni]);
      __syncthreads();
      buf ^= 1;
    }

    // ---- coalesced epilogue: 4 slabs of 32 rows through LDS ----
    float biasv[4];
    #pragma unroll
    for (int ni = 0; ni < 4; ++ni) {
      int v = n0 + wc * 64 + ni * 16 + row_in;
      biasv[ni] = (v < V_) ? bout[v] : 0.f;
    }
    float* ldsf = (float*)smem;   // [32][134] f32 = 17152B, reuses ldsA/B
    #pragma unroll
    for (int s4 = 0; s4 < 4; ++s4) {
      if (wr == (s4 >> 1)) {
        #pragma unroll
        for (int mloc = 0; mloc < 2; ++mloc) {
          const int mi = (s4 & 1) * 2 + mloc;
          #pragma unroll
          for (int ni = 0; ni < 4; ++ni)
            #pragma unroll
            for (int r = 0; r < 4; ++r)
              ldsf[(mloc * 16 + kgrp * 4 + r) * 134 + wc * 64 + ni * 16 + row_in]
                  = acc[mi][ni][r] + biasv[ni];
        }
      }
      __syncthreads();
      {
        const int row_l = tid >> 3;     // 0..31
        const int cg = tid & 7;         // 16-col group
        const int m = s4 * 32 + row_l;
        const int tt = t0 + (m >> 4);
        const int bb_ = gang * 16 + (m & 15);
        float* orow = out + ((size_t)bb_ * T_ + tt) * V_;
        const int v0 = n0 + cg * 16;
        const float* src = ldsf + row_l * 134 + cg * 16;
        if (v0 + 15 < V_) {
          #pragma unroll
          for (int k = 0; k < 8; ++k)
            *(float2*)(orow + v0 + k * 2) = *(const float2*)(src + k * 2);
        } else {
          for (int e = 0; e < 16 && v0 + e < V_; ++e)
            orow[v0 + e] = src[e];
        }
      }
      __syncthreads();
    }
  }
}

// ---------------------------------------------------------------------------
extern "C" void kernel_launch(void* const* d_in, const int* in_sizes, int n_in,
                              void* d_out, int out_size, void* d_ws, size_t ws_size,
                              hipStream_t stream) {
  const float* z     = (const float*)d_in[0];
  const int*   targ  = (const int*)d_in[1];
  const float* emb   = (const float*)d_in[2];
  const float* W_ih0 = (const float*)d_in[3];
  const float* W_hh0 = (const float*)d_in[4];
  const float* b_ih0 = (const float*)d_in[5];
  const float* b_hh0 = (const float*)d_in[6];
  const float* W_ih1 = (const float*)d_in[7];
  const float* W_hh1 = (const float*)d_in[8];
  const float* b_ih1 = (const float*)d_in[9];
  const float* b_hh1 = (const float*)d_in[10];
  const float* W_out = (const float*)d_in[11];
  const float* b_out = (const float*)d_in[12];
  const float* W_lat = (const float*)d_in[13];
  const float* b_lat = (const float*)d_in[14];
  float* out = (float*)d_out;

  char* ws = (char*)d_ws;
  __hip_bfloat16* h0hi  = (__hip_bfloat16*)(ws);              // 4,259,840
  __hip_bfloat16* h0res = (__hip_bfloat16*)(ws + 4259840);
  __hip_bfloat16* hshi  = (__hip_bfloat16*)(ws + 8519680);
  __hip_bfloat16* hsres = (__hip_bfloat16*)(ws + 12779520);
  __hip_bfloat16* embB  = (__hip_bfloat16*)(ws + 17039360);   // 15,627,264
  __hip_bfloat16* Wih0B = (__hip_bfloat16*)(ws + 32666624);   // 524,288
  __hip_bfloat16* Whh0B = (__hip_bfloat16*)(ws + 33190912);
  __hip_bfloat16* Wih1B = (__hip_bfloat16*)(ws + 33715200);
  __hip_bfloat16* Whh1B = (__hip_bfloat16*)(ws + 34239488);
  __hip_bfloat16* WoutB = (__hip_bfloat16*)(ws + 34763776);   // 15,627,264
  int* flags    = (int*)(ws + 50391040);                      // 8192 ints
  int* tickets  = flags + 8192;                               // 256 ints
  int* gqx      = flags + 8448;                               // 256 ints
  int* hsdone_g = flags + 8704;                               // 16384 ints

  reset_cnt<<<98, 256, 0, stream>>>(flags);
  conv_all<<<8144, 256, 0, stream>>>(emb, W_ih0, W_hh0, W_ih1, W_hh1, W_out,
                                     embB, Wih0B, Whh0B, Wih1B, Whh1B, WoutB);
  init_kernel<<<128, 256, 0, stream>>>(z, W_lat, b_lat, h0hi, h0res, hshi, hsres);

  fused<<<768, 256, 0, stream>>>(
      targ, embB,
      Wih0B, Whh0B, b_ih0, b_hh0,
      Wih1B, Whh1B, b_ih1, b_hh1,
      h0hi, h0res, hshi, hsres,
      WoutB, b_out, out,
      flags, tickets, gqx, hsdone_g);
}

// Round 23
// 886.232 us; speedup vs baseline: 2.3877x; 1.0356x over previous
//
#include <hip/hip_runtime.h>
#include <hip/hip_bf16.h>

#define B_ 128
#define T_ 64
#define H_ 256
#define E_ 256
#define L_ 512
#define V_ 30522
#define EOS_ 2
#define BH_ (B_ * H_)
#define NTILE_N 239
#define TILES_PER_XCD (8 * NTILE_N)   // 8 slot-groups x 239 N-tiles

typedef __attribute__((ext_vector_type(8))) short bf16x8;
typedef __attribute__((ext_vector_type(4))) float f32x4;

__device__ __forceinline__ float4 ld4(const float* p) { return *(const float4*)p; }
__device__ __forceinline__ float dot4(float4 a, float4 b) {
  return a.x * b.x + a.y * b.y + a.z * b.z + a.w * b.w;
}
__device__ __forceinline__ float sigf(float x) {
  return __builtin_amdgcn_rcpf(1.f + __expf(-x));
}
__device__ __forceinline__ float tanh_fast(float x) {
  float e = __expf(2.f * x);
  return 1.f - 2.f * __builtin_amdgcn_rcpf(e + 1.f);
}
__device__ __forceinline__ f32x4 mfma16(bf16x8 a, bf16x8 b, f32x4 c) {
  return __builtin_amdgcn_mfma_f32_16x16x32_bf16(a, b, c, 0, 0, 0);
}

// ---------------------------------------------------------------------------
// merged f32 -> bf16 convert for all 6 weight arrays (one launch)
// ---------------------------------------------------------------------------
__global__ __launch_bounds__(256) void conv_all(
    const float* __restrict__ emb, const float* __restrict__ w0i,
    const float* __restrict__ w0h, const float* __restrict__ w1i,
    const float* __restrict__ w1h, const float* __restrict__ wout,
    __hip_bfloat16* __restrict__ dEmb, __hip_bfloat16* __restrict__ dW0i,
    __hip_bfloat16* __restrict__ dW0h, __hip_bfloat16* __restrict__ dW1i,
    __hip_bfloat16* __restrict__ dW1h, __hip_bfloat16* __restrict__ dWout) {
  long i = ((long)blockIdx.x * 256 + threadIdx.x) * 8;
  const float* src; __hip_bfloat16* dst; long off;
  if (i < 7813632L)       { src = emb;  dst = dEmb;  off = i; }
  else if (i < 8075776L)  { src = w0i;  dst = dW0i;  off = i - 7813632L; }
  else if (i < 8337920L)  { src = w0h;  dst = dW0h;  off = i - 8075776L; }
  else if (i < 8600064L)  { src = w1i;  dst = dW1i;  off = i - 8337920L; }
  else if (i < 8862208L)  { src = w1h;  dst = dW1h;  off = i - 8600064L; }
  else if (i < 16675840L) { src = wout; dst = dWout; off = i - 8862208L; }
  else return;
  float4 lo = ld4(src + off), hi = ld4(src + off + 4);
  union { bf16x8 v8; __hip_bfloat16 e[8]; } u;
  u.e[0] = __float2bfloat16(lo.x); u.e[1] = __float2bfloat16(lo.y);
  u.e[2] = __float2bfloat16(lo.z); u.e[3] = __float2bfloat16(lo.w);
  u.e[4] = __float2bfloat16(hi.x); u.e[5] = __float2bfloat16(hi.y);
  u.e[6] = __float2bfloat16(hi.z); u.e[7] = __float2bfloat16(hi.w);
  *(bf16x8*)(dst + off) = u.v8;
}

// zero flags(8192)+tickets(256)+gqx(256)+hsdone_g(16384)+gangdone(256)=25344
__global__ __launch_bounds__(256) void reset_cnt(int* __restrict__ c) {
  int i = blockIdx.x * 256 + threadIdx.x;
  if (i < 25344) c[i] = 0;
}

// ---------------------------------------------------------------------------
// init: h_init = z @ W_lat^T + b_lat -> slot 0 of h0 & hs (hi+res)
// ---------------------------------------------------------------------------
__global__ __launch_bounds__(256) void init_kernel(
    const float* __restrict__ z, const float* __restrict__ W_lat,
    const float* __restrict__ b_lat,
    __hip_bfloat16* __restrict__ h0hi, __hip_bfloat16* __restrict__ h0res,
    __hip_bfloat16* __restrict__ hshi, __hip_bfloat16* __restrict__ hsres) {
  int b = blockIdx.x;
  int h = threadIdx.x;
  const float* zr = z + (size_t)b * L_;
  const float* wr = W_lat + (size_t)h * L_;
  float acc = b_lat[h];
  #pragma unroll 4
  for (int l = 0; l < L_; l += 4) acc += dot4(ld4(zr + l), ld4(wr + l));
  __hip_bfloat16 hi = __float2bfloat16(acc);
  __hip_bfloat16 re = __float2bfloat16(acc - __bfloat162float(hi));
  int idx = b * H_ + h;
  h0hi[idx] = hi; h0res[idx] = re;
  hshi[idx] = hi; hsres[idx] = re;
}

// ---------------------------------------------------------------------------
// FUSED persistent kernel, SAME-XCD producer->consumer (R18-R20 structure).
// R23 = R20 exact (plain float2 epilogue stores; plain ticket order -- the
// R22 B-pairing cut FETCH but not time) + GEMM THROTTLE: per XCD, only
// roles 32..63 run gemm during the recurrence; roles >= 64 sleep on a
// per-gang completion counter (3.4us-cadence poll, negligible traffic) and
// join when the gang's 32 lstm blocks finish. Rationale: gemm was at ~45%
// duty cycle (over-provisioned) while its staging bursts stretched the
// recurrence 500 -> ~840us. Deadlock-free: sleepers wait only on lstm
// completion; spin cap -> early join (harmless interference, not a hang).
// Sync transport FROZEN. NT stores BANNED (R15/R21: 1.4-3x write amp).
// ---------------------------------------------------------------------------
__global__ __launch_bounds__(256, 3) void fused(
    const int* __restrict__ targ, const __hip_bfloat16* __restrict__ embB,
    const __hip_bfloat16* __restrict__ Wih0B, const __hip_bfloat16* __restrict__ Whh0B,
    const float* __restrict__ b_ih0, const float* __restrict__ b_hh0,
    const __hip_bfloat16* __restrict__ Wih1B, const __hip_bfloat16* __restrict__ Whh1B,
    const float* __restrict__ b_ih1, const float* __restrict__ b_hh1,
    __hip_bfloat16* __restrict__ h0hi, __hip_bfloat16* __restrict__ h0res,
    __hip_bfloat16* __restrict__ hshi, __hip_bfloat16* __restrict__ hsres,
    const __hip_bfloat16* __restrict__ Wb, const float* __restrict__ bout,
    float* __restrict__ out,
    int* __restrict__ flags, int* __restrict__ tickets,
    int* __restrict__ gqx, int* __restrict__ hsdone_g, int* __restrict__ gangdone) {
  __shared__ int role_sh, gang_sh, tile_sh;
  __shared__ char smem[32768];

  const int tid = threadIdx.x;
  if (tid == 0) {
    unsigned xcd;
    asm volatile("s_getreg_b32 %0, hwreg(HW_REG_XCC_ID)" : "=s"(xcd));
    xcd &= 7u;
    role_sh = __hip_atomic_fetch_add(tickets + xcd * 32, 1, __ATOMIC_RELAXED,
                                     __HIP_MEMORY_SCOPE_AGENT);
    gang_sh = (int)xcd;
  }
  __syncthreads();
  const int role = role_sh;
  const int gang = gang_sh;
  const int lane = tid & 63;

  if (role < 32) {
    // ================= LSTM worker (R13-exact math, priority-boosted) ======
    __builtin_amdgcn_s_setprio(1);
    const bool isL0 = role < 16;
    const int chunk = role & 15;
    int* flag0 = flags + gang * 1024;
    int* flag1 = flag0 + 512;

    const int wave = tid >> 6;
    const int arow = lane & 15;
    const int klo = lane >> 4;
    const int hcol = chunk * 16 + arow;
    const int brow0 = gang * 16;
    const int myrow = brow0 + arow;

    const __hip_bfloat16* W1 = isL0 ? Wih0B : Wih1B;
    const __hip_bfloat16* W2 = isL0 ? Whh0B : Whh1B;
    bf16x8 bw1[8], bw2[8];
    {
      const size_t wrow = (size_t)(wave * 256 + hcol) * 256;
      #pragma unroll
      for (int ks = 0; ks < 8; ++ks) {
        bw1[ks] = *(const bf16x8*)(W1 + wrow + ks * 32 + klo * 8);
        bw2[ks] = *(const bf16x8*)(W2 + wrow + ks * 32 + klo * 8);
      }
    }

    const int erow = tid >> 4;
    const int ecol = tid & 15;
    const float* bi = isL0 ? b_ih0 : b_ih1;
    const float* bh = isL0 ? b_hh0 : b_hh1;
    const int ehcol = chunk * 16 + ecol;
    const float bias_i = bi[ehcol] + bh[ehcol];
    const float bias_f = bi[256 + ehcol] + bh[256 + ehcol];
    const float bias_g = bi[512 + ehcol] + bh[512 + ehcol];
    const float bias_o = bi[768 + ehcol] + bh[768 + ehcol];
    float c_state = 0.f;

    typedef float GL[16][17];
    GL* glds = (GL*)smem;

    for (int t = 0; t < T_; ++t) {
      {
        const int need0 = isL0 ? t : t + 1;
        const int need1 = isL0 ? 0 : t;
        if (tid < 64) {
          int* p = nullptr; int need = 0;
          if (lane < 16) { p = flag0 + lane * 32; need = need0; }
          else if (lane < 32) { p = flag1 + (lane - 16) * 32; need = need1; }
          int it = 0;
          for (;;) {
            bool ok = true;
            if (p && need > 0) ok = (atomicAdd(p, 0) >= need);
            if (__all(ok)) break;
            if (++it >= (1 << 15)) break;   // loud failure, not a hang
            __builtin_amdgcn_s_sleep(1);
          }
        }
        __syncthreads();
      }

      f32x4 acc0 = (f32x4){0.f, 0.f, 0.f, 0.f};
      f32x4 acc1 = (f32x4){0.f, 0.f, 0.f, 0.f};
      if (isL0) {
        int tok = (t == 0) ? EOS_ : targ[myrow * T_ + t - 1];
        const __hip_bfloat16* xp = embB + (size_t)tok * E_;
        const __hip_bfloat16* hhp = h0hi + (size_t)t * BH_ + myrow * H_;
        const __hip_bfloat16* hrp = h0res + (size_t)t * BH_ + myrow * H_;
        #pragma unroll
        for (int ks = 0; ks < 8; ++ks) {
          const int ko = ks * 32 + klo * 8;
          bf16x8 ax = *(const bf16x8*)(xp + ko);
          bf16x8 ahh = *(const bf16x8*)(hhp + ko);
          bf16x8 ahr = *(const bf16x8*)(hrp + ko);
          if (ks & 1) {
            acc1 = mfma16(ax, bw1[ks], acc1);
            acc1 = mfma16(ahh, bw2[ks], acc1);
            acc1 = mfma16(ahr, bw2[ks], acc1);
          } else {
            acc0 = mfma16(ax, bw1[ks], acc0);
            acc0 = mfma16(ahh, bw2[ks], acc0);
            acc0 = mfma16(ahr, bw2[ks], acc0);
          }
        }
      } else {
        const __hip_bfloat16* xhp = h0hi + (size_t)(t + 1) * BH_ + myrow * H_;
        const __hip_bfloat16* xrp = h0res + (size_t)(t + 1) * BH_ + myrow * H_;
        const __hip_bfloat16* hhp = hshi + (size_t)t * BH_ + myrow * H_;
        const __hip_bfloat16* hrp = hsres + (size_t)t * BH_ + myrow * H_;
        #pragma unroll
        for (int ks = 0; ks < 8; ++ks) {
          const int ko = ks * 32 + klo * 8;
          bf16x8 axh = *(const bf16x8*)(xhp + ko);
          bf16x8 axr = *(const bf16x8*)(xrp + ko);
          bf16x8 ahh = *(const bf16x8*)(hhp + ko);
          bf16x8 ahr = *(const bf16x8*)(hrp + ko);
          if (ks & 1) {
            acc1 = mfma16(axh, bw1[ks], acc1);
            acc1 = mfma16(axr, bw1[ks], acc1);
            acc1 = mfma16(ahh, bw2[ks], acc1);
            acc1 = mfma16(ahr, bw2[ks], acc1);
          } else {
            acc0 = mfma16(axh, bw1[ks], acc0);
            acc0 = mfma16(axr, bw1[ks], acc0);
            acc0 = mfma16(ahh, bw2[ks], acc0);
            acc0 = mfma16(ahr, bw2[ks], acc0);
          }
        }
      }
      #pragma unroll
      for (int r = 0; r < 4; ++r)
        glds[tid >> 6][klo * 4 + r][arow] = acc0[r] + acc1[r];
      __syncthreads();

      {
        float gi = glds[0][erow][ecol] + bias_i;
        float gf = glds[1][erow][ecol] + bias_f;
        float gg = glds[2][erow][ecol] + bias_g;
        float go = glds[3][erow][ecol] + bias_o;
        float iv = sigf(gi), fv = sigf(gf), gv = tanh_fast(gg), ov = sigf(go);
        c_state = fv * c_state + iv * gv;
        float h = ov * tanh_fast(c_state);
        __hip_bfloat16 hi = __float2bfloat16(h);
        __hip_bfloat16 re = __float2bfloat16(h - __bfloat162float(hi));
        size_t off = (size_t)(t + 1) * BH_ + (size_t)(brow0 + erow) * H_ + ehcol;
        (isL0 ? h0hi : hshi)[off] = hi;
        (isL0 ? h0res : hsres)[off] = re;
      }

      __syncthreads();   // vmcnt drain: stores are in this XCD's L2
      if (tid == 0) {
        atomicAdd((isL0 ? flag0 : flag1) + chunk * 32, 1);
        if (!isL0) atomicAdd(hsdone_g + (gang * 64 + t) * 32, 1);
      }
    }
    __builtin_amdgcn_s_setprio(0);
    if (tid == 0) atomicAdd(gangdone + gang * 32, 1);   // release sleepers
    // fall through: finished lstm workers join this XCD's gemm pool
  } else if (role >= 64) {
    // ============ throttled gemm worker: sleep until gang done ============
    if (tid == 0) {
      int it = 0;
      while (atomicAdd(gangdone + gang * 32, 0) < 32 && it < (1 << 10)) {
        __builtin_amdgcn_s_sleep(127);
        ++it;
      }
    }
    __syncthreads();
  }

  // ================= GEMM worker (same-XCD tiles only) =================
  __hip_bfloat16* ldsA = (__hip_bfloat16*)smem;            // [2][4096]
  __hip_bfloat16* ldsB = (__hip_bfloat16*)(smem + 16384);  // [2][4096]
  const int wave = tid >> 6;
  const int wr = wave >> 1, wc = wave & 1;
  const int row_in = lane & 15;
  const int kgrp = lane >> 4;

  for (;;) {
    if (tid == 0) tile_sh = atomicAdd(gqx + gang * 32, 1);
    __syncthreads();
    const int tau = tile_sh;
    if (tau >= TILES_PER_XCD) return;
    const int sg = tau / NTILE_N;          // slot group: t = sg*8 .. sg*8+7
    const int nt = tau - sg * NTILE_N;
    const int n0 = nt * 128;
    const int t0 = sg * 8;

    // wait: last slot of the group done (monotone completion subsumes rest)
    if (tid == 0) {
      int* p = hsdone_g + (gang * 64 + t0 + 7) * 32;
      int it = 0;
      while (atomicAdd(p, 0) < 16 && it < (1 << 15)) {
        __builtin_amdgcn_s_sleep(32);
        ++it;
      }
    }
    __syncthreads();

    // A row r (0..127): t = t0 + (r>>4), b = gang*16 + (r&15)
    auto stage = [&](int kb, int buf) {
      #pragma unroll
      for (int p = 0; p < 2; ++p) {
        int slot = p * 256 + wave * 64 + lane;
        int row = slot >> 2;
        int kd = ((slot & 3) + (row >> 1)) & 3;   // swizzled source granule
        const __hip_bfloat16* srcA =
            hshi + (size_t)(t0 + (row >> 4) + 1) * BH_ +
            (size_t)(gang * 16 + (row & 15)) * H_ + kb * 32 + kd * 8;
        int rn = n0 + row; if (rn >= V_) rn = V_ - 1;
        const __hip_bfloat16* srcB = Wb + (size_t)rn * H_ + kb * 32 + kd * 8;
        __hip_bfloat16* dstA = ldsA + buf * 4096 + (p * 2048 + wave * 512);
        __hip_bfloat16* dstB = ldsB + buf * 4096 + (p * 2048 + wave * 512);
        __builtin_amdgcn_global_load_lds(
            (const __attribute__((address_space(1))) unsigned int*)srcA,
            (__attribute__((address_space(3))) unsigned int*)dstA, 16, 0, 0);
        __builtin_amdgcn_global_load_lds(
            (const __attribute__((address_space(1))) unsigned int*)srcB,
            (__attribute__((address_space(3))) unsigned int*)dstB, 16, 0, 0);
      }
    };

    f32x4 acc[4][4];
    #pragma unroll
    for (int i = 0; i < 4; ++i)
      #pragma unroll
      for (int j = 0; j < 4; ++j) acc[i][j] = (f32x4){0.f, 0.f, 0.f, 0.f};

    stage(0, 0);
    __syncthreads();

    int buf = 0;
    for (int kb = 0; kb < 8; ++kb) {
      if (kb < 7) stage(kb + 1, buf ^ 1);
      bf16x8 a[4], b[4];
      #pragma unroll
      for (int mi = 0; mi < 4; ++mi) {
        int row = wr * 64 + mi * 16 + row_in;
        int g = (kgrp - (row >> 1)) & 3;
        a[mi] = *(const bf16x8*)(ldsA + buf * 4096 + row * 32 + g * 8);
      }
      #pragma unroll
      for (int ni = 0; ni < 4; ++ni) {
        int row = wc * 64 + ni * 16 + row_in;
        int g = (kgrp - (row >> 1)) & 3;
        b[ni] = *(const bf16x8*)(ldsB + buf * 4096 + row * 32 + g * 8);
      }
      #pragma unroll
      for (int mi = 0; mi < 4; ++mi)
        #pragma unroll
        for (int ni = 0; ni < 4; ++ni)
          acc[mi][ni] = mfma16(a[mi], b[ni], acc[mi][ni]);
      __syncthreads();
      buf ^= 1;
    }

    // ---- coalesced epilogue: 4 slabs of 32 rows through LDS ----
    float biasv[4];
    #pragma unroll
    for (int ni = 0; ni < 4; ++ni) {
      int v = n0 + wc * 64 + ni * 16 + row_in;
      biasv[ni] = (v < V_) ? bout[v] : 0.f;
    }
    float* ldsf = (float*)smem;   // [32][134] f32 = 17152B, reuses ldsA/B
    #pragma unroll
    for (int s4 = 0; s4 < 4; ++s4) {
      if (wr == (s4 >> 1)) {
        #pragma unroll
        for (int mloc = 0; mloc < 2; ++mloc) {
          const int mi = (s4 & 1) * 2 + mloc;
          #pragma unroll
          for (int ni = 0; ni < 4; ++ni)
            #pragma unroll
            for (int r = 0; r < 4; ++r)
              ldsf[(mloc * 16 + kgrp * 4 + r) * 134 + wc * 64 + ni * 16 + row_in]
                  = acc[mi][ni][r] + biasv[ni];
        }
      }
      __syncthreads();
      {
        const int row_l = tid >> 3;     // 0..31
        const int cg = tid & 7;         // 16-col group
        const int m = s4 * 32 + row_l;
        const int tt = t0 + (m >> 4);
        const int bb_ = gang * 16 + (m & 15);
        float* orow = out + ((size_t)bb_ * T_ + tt) * V_;
        const int v0 = n0 + cg * 16;
        const float* src = ldsf + row_l * 134 + cg * 16;
        if (v0 + 15 < V_) {
          #pragma unroll
          for (int k = 0; k < 8; ++k)
            *(float2*)(orow + v0 + k * 2) = *(const float2*)(src + k * 2);
        } else {
          for (int e = 0; e < 16 && v0 + e < V_; ++e)
            orow[v0 + e] = src[e];
        }
      }
      __syncthreads();
    }
  }
}

// ---------------------------------------------------------------------------
extern "C" void kernel_launch(void* const* d_in, const int* in_sizes, int n_in,
                              void* d_out, int out_size, void* d_ws, size_t ws_size,
                              hipStream_t stream) {
  const float* z     = (const float*)d_in[0];
  const int*   targ  = (const int*)d_in[1];
  const float* emb   = (const float*)d_in[2];
  const float* W_ih0 = (const float*)d_in[3];
  const float* W_hh0 = (const float*)d_in[4];
  const float* b_ih0 = (const float*)d_in[5];
  const float* b_hh0 = (const float*)d_in[6];
  const float* W_ih1 = (const float*)d_in[7];
  const float* W_hh1 = (const float*)d_in[8];
  const float* b_ih1 = (const float*)d_in[9];
  const float* b_hh1 = (const float*)d_in[10];
  const float* W_out = (const float*)d_in[11];
  const float* b_out = (const float*)d_in[12];
  const float* W_lat = (const float*)d_in[13];
  const float* b_lat = (const float*)d_in[14];
  float* out = (float*)d_out;

  char* ws = (char*)d_ws;
  __hip_bfloat16* h0hi  = (__hip_bfloat16*)(ws);              // 4,259,840
  __hip_bfloat16* h0res = (__hip_bfloat16*)(ws + 4259840);
  __hip_bfloat16* hshi  = (__hip_bfloat16*)(ws + 8519680);
  __hip_bfloat16* hsres = (__hip_bfloat16*)(ws + 12779520);
  __hip_bfloat16* embB  = (__hip_bfloat16*)(ws + 17039360);   // 15,627,264
  __hip_bfloat16* Wih0B = (__hip_bfloat16*)(ws + 32666624);   // 524,288
  __hip_bfloat16* Whh0B = (__hip_bfloat16*)(ws + 33190912);
  __hip_bfloat16* Wih1B = (__hip_bfloat16*)(ws + 33715200);
  __hip_bfloat16* Whh1B = (__hip_bfloat16*)(ws + 34239488);
  __hip_bfloat16* WoutB = (__hip_bfloat16*)(ws + 34763776);   // 15,627,264
  int* flags    = (int*)(ws + 50391040);                      // 8192 ints
  int* tickets  = flags + 8192;                               // 256 ints
  int* gqx      = flags + 8448;                               // 256 ints
  int* hsdone_g = flags + 8704;                               // 16384 ints
  int* gangdone = flags + 25088;                              // 256 ints

  reset_cnt<<<100, 256, 0, stream>>>(flags);
  conv_all<<<8144, 256, 0, stream>>>(emb, W_ih0, W_hh0, W_ih1, W_hh1, W_out,
                                     embB, Wih0B, Whh0B, Wih1B, Whh1B, WoutB);
  init_kernel<<<128, 256, 0, stream>>>(z, W_lat, b_lat, h0hi, h0res, hshi, hsres);

  fused<<<768, 256, 0, stream>>>(
      targ, embB,
      Wih0B, Whh0B, b_ih0, b_hh0,
      Wih1B, Whh1B, b_ih1, b_hh1,
      h0hi, h0res, hshi, hsres,
      WoutB, b_out, out,
      flags, tickets, gqx, hsdone_g, gangdone);
}